// Round 16
// baseline (190.799 us; speedup 1.0000x reference)
//
#include <hip/hip_runtime.h>
#include <hip/hip_bf16.h>

typedef __hip_bfloat16 bf16;
typedef unsigned short u16;
typedef unsigned int u32;
typedef float f32x4 __attribute__((ext_vector_type(4)));
typedef float f32x16 __attribute__((ext_vector_type(16)));
typedef __bf16 bf16x8 __attribute__((ext_vector_type(8)));
typedef u16 u16x8 __attribute__((ext_vector_type(8)));

#define DMODEL 1024
#define NH 16
#define HD 64
#define QK_LD 2048
#define SLEN 4096

typedef __attribute__((address_space(1))) const void* as1_cvp;
typedef __attribute__((address_space(3))) void* as3_vp;

__device__ __forceinline__ void gload_lds16(const void* g, void* l) {
  __builtin_amdgcn_global_load_lds((as1_cvp)g, (as3_vp)l, 16, 0, 0);
}

__device__ __forceinline__ f32x4 mfma16(bf16x8 a, bf16x8 b, f32x4 c) {
  return __builtin_amdgcn_mfma_f32_16x16x32_bf16(a, b, c, 0, 0, 0);
}
__device__ __forceinline__ f32x16 mfma32(bf16x8 a, bf16x8 b, f32x16 c) {
  return __builtin_amdgcn_mfma_f32_32x32x16_bf16(a, b, c, 0, 0, 0);
}

// raw hardware exp2 (v_exp_f32), no denormal-guard expansion
__device__ __forceinline__ float fexp2(float x) {
#if __has_builtin(__builtin_amdgcn_exp2f)
  return __builtin_amdgcn_exp2f(x);
#else
  return __expf(x * 0.6931471805599453f);
#endif
}

__device__ __forceinline__ u16 f2b(float f) {
  union { bf16 b; u16 s; } u; u.b = __float2bfloat16(f); return u.s;
}
__device__ __forceinline__ u32 pkbf(float a, float b) {
  union { __hip_bfloat162 h; u32 u; } cv;
  cv.h = __float22bfloat162_rn(make_float2(a, b));
  return cv.u;
}

// ---------------- fp32 -> bf16 conversion, 4 elems/thread ----------------
__global__ __launch_bounds__(256) void cvt_kernel(const float* __restrict__ src,
                                                  bf16* __restrict__ dst, int n) {
  int i = (blockIdx.x * 256 + threadIdx.x) * 4;
  if (i >= n) return;
  float4 v = *(const float4*)(src + i);
  union { ushort4 u; bf16 h[4]; } o;
  o.h[0] = __float2bfloat16(v.x);
  o.h[1] = __float2bfloat16(v.y);
  o.h[2] = __float2bfloat16(v.z);
  o.h[3] = __float2bfloat16(v.w);
  *(ushort4*)(dst + i) = o.u;
}

// ---------------- RoPE on QK buffer [4096][2048], in place ----------------
// Q region also scaled by 0.125*log2(e): scores in log2 domain.
__global__ __launch_bounds__(256) void rope_kernel(bf16* __restrict__ qk) {
  int idx = blockIdx.x * 256 + threadIdx.x;
  int p = idx & 511;
  int s = (idx >> 9) & 4095;
  int region = idx >> 21;              // 0 = Q, 1 = K
  int i = p & 31;
  int h = p >> 5;
  long base = (long)s * QK_LD + region * DMODEL + h * HD + 2 * i;
  float x1 = __bfloat162float(qk[base]);
  float x2 = __bfloat162float(qk[base + 1]);
  float invf = powf(10000.0f, -(float)(2 * i) / 64.0f);
  float ang = (float)s * invf;
  float sn, cs;
  sincosf(ang, &sn, &cs);
  float scale = (region == 0) ? 0.18033688011112042f : 1.0f;  // 0.125*log2(e)
  float r1 = (x1 * cs - x2 * sn) * scale;
  float r2 = (x1 * sn + x2 * cs) * scale;
  qk[base]     = __float2bfloat16(r1);
  qk[base + 1] = __float2bfloat16(r2);
}

// ---------------- NT GEMM: C[M,N] = A[M,K] * B[N,K]^T (unchanged) ---------
template <int OUT_BF16>
__global__ __launch_bounds__(256) void gemm_bt(const bf16* __restrict__ A,
                                               const bf16* __restrict__ B,
                                               void* __restrict__ Cout,
                                               const float* __restrict__ bias,
                                               int M, int N, int K) {
  __shared__ __align__(16) bf16 As[128 * 32];
  __shared__ __align__(16) bf16 Bs[128 * 32];
  const int tid = threadIdx.x;
  const int lane = tid & 63;
  const int wid = tid >> 6;
  const int brow = blockIdx.y * 128;
  const int bcol = blockIdx.x * 128;
  const int wr = wid >> 1, wc = wid & 1;

  f32x4 acc[4][4] = {};

  const int srow = lane >> 2;
  const int scol = (lane & 3) * 8;
  const bf16* Ag = A + (long)(brow + wid * 32 + srow) * K + scol;
  const bf16* Bg = B + (long)(bcol + wid * 32 + srow) * K + scol;
  bf16* AsW = As + wid * 32 * 32;
  bf16* BsW = Bs + wid * 32 * 32;
  const int kof = (lane >> 4) * 8;
  const int r16 = lane & 15;

  for (int k0 = 0; k0 < K; k0 += 32) {
    __syncthreads();
    gload_lds16(Ag + k0, AsW);
    gload_lds16(Ag + k0 + (long)16 * K, AsW + 16 * 32);
    gload_lds16(Bg + k0, BsW);
    gload_lds16(Bg + k0 + (long)16 * K, BsW + 16 * 32);
    __syncthreads();
    bf16x8 af[4], bfr[4];
#pragma unroll
    for (int m = 0; m < 4; ++m)
      af[m] = *(const bf16x8*)(As + (wr * 64 + m * 16 + r16) * 32 + kof);
#pragma unroll
    for (int n = 0; n < 4; ++n)
      bfr[n] = *(const bf16x8*)(Bs + (wc * 64 + n * 16 + r16) * 32 + kof);
#pragma unroll
    for (int m = 0; m < 4; ++m)
#pragma unroll
      for (int n = 0; n < 4; ++n)
        acc[m][n] = mfma16(af[m], bfr[n], acc[m][n]);
  }

  const int r0 = (lane >> 4) * 4;
#pragma unroll
  for (int m = 0; m < 4; ++m) {
#pragma unroll
    for (int n = 0; n < 4; ++n) {
      int row = brow + wr * 64 + m * 16 + r0;
      int col = bcol + wc * 64 + n * 16 + r16;
#pragma unroll
      for (int r = 0; r < 4; ++r) {
        if (OUT_BF16) {
          ((bf16*)Cout)[(long)(row + r) * N + col] = __float2bfloat16(acc[m][n][r]);
        } else {
          ((float*)Cout)[(long)(row + r) * N + col] = acc[m][n][r] + bias[col];
        }
      }
    }
  }
}

// ---------------- causal flash attention (v13) ----------------
// v11's split-KV wave pairs + max-tracked softmax (proven 0.0156 numerics)
// + v12's structural win: V PRE-TRANSPOSED by the V^T GEMM, staged with 2
// global_load_lds (pre-swizzled source) exactly like K — the per-iteration
// 16-scalar-load V gather is gone. Fixed-cap softmax REFUTED (R14: absmax
// 0.071 > 0.0597 — p=1.0-exact anchoring of max-tracking matters).
__global__ __launch_bounds__(256, 4) void attn_kernel(const bf16* __restrict__ qk,
                                                      const bf16* __restrict__ vt,
                                                      bf16* __restrict__ ctx) {
  __shared__ __align__(16) bf16 smem[16384];   // 32 KB
  bf16 (*Ks)[64][64] = (bf16(*)[64][64])(smem);          // 2 bufs, [kv][d]
  bf16 (*Vt)[64][64] = (bf16(*)[64][64])(smem + 8192);   // 2 bufs, [d][kv]

  const int tid = threadIdx.x;
  const int lane = tid & 63;
  const int wid = tid >> 6;            // 0..3
  const int hi = lane >> 5;
  const int l31 = lane & 31;
  const int t = blockIdx.x >> 4;       // 0..63
  const int h = blockIdx.x & 15;
  const int p = wid & 1;               // kv-half parity within the tile pair
  const int qblk = (wid < 2) ? (127 - t) : t;   // 32-row q tile
  const int q0w = qblk * 32;
  const long kcol = DMODEL + (long)h * HD;      // K region in qk rows

  // Q B-fragments: lane holds Q[q=l31][d = kt*16 + hi*8 .. +8]
  bf16x8 qf[4];
  {
    const bf16* qp = qk + (long)(q0w + l31) * QK_LD + h * HD + hi * 8;
#pragma unroll
    for (int kt = 0; kt < 4; ++kt) qf[kt] = *(const bf16x8*)(qp + kt * 16);
  }

  const int kOff = ((lane & 7) ^ (lane >> 3)) * 8;   // pre-swizzled src slot
  const int lr = lane >> 3;
  const int srowp = (lr & 3) + 8 * (lr >> 2);        // sigma base for K rows

  // hoisted swizzled LDS element offsets
  int kro[4];
#pragma unroll
  for (int kt = 0; kt < 4; ++kt)
    kro[kt] = l31 * 64 + ((((kt << 1) | hi) ^ (l31 & 7)) * 8);
  const int vbase = l31 * 64;
  const int vslotx = l31 & 7;

  // V^T source rows for this block's head
  const bf16* vth = vt + (long)h * HD * SLEN;

  f32x16 acc[2] = {};
  float m_r = -1e30f, l_r = 0.0f;      // own-lane online-softmax state

  const int nkb = (129 - t) >> 1;      // 64-row KV blocks covering heavy tile
  const int vR = lane >> 3;            // V stage: row within 8-row chunk

  // prologue: stage KV block 0 into buf 0 (K sigma rows; V^T rows direct)
  {
#pragma unroll
    for (int c2 = 0; c2 < 2; ++c2) {
      const int c = wid * 2 + c2;
      const int sub = c >> 2, cc = c & 3;
      gload_lds16(qk + (long)(sub * 32 + srowp + 4 * (cc & 1) + 16 * (cc >> 1)) * QK_LD + kcol + kOff,
                  &Ks[0][c * 8][0]);
    }
#pragma unroll
    for (int c2 = 0; c2 < 2; ++c2) {
      const int d0 = wid * 16 + c2 * 8;
      gload_lds16(vth + (long)(d0 + vR) * SLEN + kOff, &Vt[0][d0][0]);
    }
  }

  for (int kb = 0; kb < nkb; ++kb) {
    const int cur = kb & 1;
    const int kvs = kb * 64 + p * 32;   // this wave's sub
    const bool pre = (kb + 1 < nkb);
    __syncthreads();   // staging of block kb visible; prev iter reads done

    // prefetch next KV block into the other buffer (async, no reg staging)
    if (pre) {
      const long kvn = (long)(kb + 1) * 64;
#pragma unroll
      for (int c2 = 0; c2 < 2; ++c2) {
        const int c = wid * 2 + c2;
        const int sub = c >> 2, cc = c & 3;
        gload_lds16(qk + (kvn + sub * 32 + srowp + 4 * (cc & 1) + 16 * (cc >> 1)) * QK_LD + kcol + kOff,
                    &Ks[cur ^ 1][c * 8][0]);
      }
#pragma unroll
      for (int c2 = 0; c2 < 2; ++c2) {
        const int d0 = wid * 16 + c2 * 8;
        gload_lds16(vth + (long)(d0 + vR) * SLEN + kvn + kOff, &Vt[cur ^ 1][d0][0]);
      }
    }

    if (kvs <= q0w + 31) {   // wave-uniform activity test
      const bf16* KsC = &Ks[cur][0][0];
      const bf16* VtC = &Vt[cur][0][0];

      // S^T = K * Q^T over d=64 (4 mfma of k=16) on this wave's sub
      f32x16 c16 = {};
      __builtin_amdgcn_s_setprio(1);
#pragma unroll
      for (int kt = 0; kt < 4; ++kt) {
        bf16x8 kf = *(const bf16x8*)(KsC + p * 2048 + kro[kt]);
        c16 = mfma32(kf, qf[kt], c16);
      }
      __builtin_amdgcn_s_setprio(0);

      // causal mask; kv of reg r under sigma:
      // kv = kvs + (r&3) + 4*((r>>2)&1) + 8*hi + 16*(r>>3)
      if (kvs + 31 > q0w) {
        const int q = q0w + l31;
        const int kvb = kvs + 8 * hi;
#pragma unroll
        for (int r = 0; r < 16; ++r) {
          int kv = kvb + (r & 3) + 4 * ((r >> 2) & 1) + 16 * (r >> 3);
          if (kv > q) c16[r] = -1e30f;
        }
      }

      // per-lane online softmax; pair (l, l^32) holds the 32 kv of this sub
      float x0 = fmaxf(fmaxf(c16[0], c16[1]), fmaxf(c16[2], c16[3]));
      float x1 = fmaxf(fmaxf(c16[4], c16[5]), fmaxf(c16[6], c16[7]));
      float x2 = fmaxf(fmaxf(c16[8], c16[9]), fmaxf(c16[10], c16[11]));
      float x3 = fmaxf(fmaxf(c16[12], c16[13]), fmaxf(c16[14], c16[15]));
      float pmax = fmaxf(fmaxf(x0, x1), fmaxf(x2, x3));
      pmax = fmaxf(pmax, __shfl_xor(pmax, 32, 64));

      if (!__all(pmax <= m_r + 11.0f)) {   // defer-max (log2 units)
        float mn = fmaxf(m_r, pmax);
        float al = fexp2(m_r - mn);
        m_r = mn;
        l_r *= al;
#pragma unroll
        for (int dt = 0; dt < 2; ++dt)
#pragma unroll
          for (int r = 0; r < 16; ++r) acc[dt][r] *= al;
      }

      float pa[16];
#pragma unroll
      for (int r = 0; r < 16; ++r) pa[r] = fexp2(c16[r] - m_r);
      float rs = ((pa[0] + pa[1]) + (pa[2] + pa[3])) + ((pa[4] + pa[5]) + (pa[6] + pa[7])) +
                 (((pa[8] + pa[9]) + (pa[10] + pa[11])) + ((pa[12] + pa[13]) + (pa[14] + pa[15])));
      l_r += rs;

      // P^T -> B-fragments: straight in-order pairwise packs (sigma layout)
      union BP { u32 u[4]; bf16x8 v; } f0, f1;
      f0.u[0] = pkbf(pa[0], pa[1]);   f0.u[1] = pkbf(pa[2], pa[3]);
      f0.u[2] = pkbf(pa[4], pa[5]);   f0.u[3] = pkbf(pa[6], pa[7]);
      f1.u[0] = pkbf(pa[8], pa[9]);   f1.u[1] = pkbf(pa[10], pa[11]);
      f1.u[2] = pkbf(pa[12], pa[13]); f1.u[3] = pkbf(pa[14], pa[15]);

      // O^T += V^T * P^T
      __builtin_amdgcn_s_setprio(1);
#pragma unroll
      for (int dt = 0; dt < 2; ++dt) {
        const bf16* vrow = VtC + dt * 2048 + vbase;
        bf16x8 v0 = *(const bf16x8*)(vrow + (((p * 4 + hi) ^ vslotx) * 8));
        acc[dt] = mfma32(v0, f0.v, acc[dt]);
        bf16x8 v1 = *(const bf16x8*)(vrow + (((p * 4 + 2 + hi) ^ vslotx) * 8));
        acc[dt] = mfma32(v1, f1.v, acc[dt]);
      }
      __builtin_amdgcn_s_setprio(0);
    }
  }

  // ---- split-KV merge: waves (0,1) and (2,3) combine (m, l, acc) ----
  __syncthreads();   // everyone done with Ks/Vt; LDS reused
  float* fs = (float*)smem;          // 2 x 64 x 34 floats = 17.4 KB merge area
  if (wid & 1) {
    float* mb = fs + (wid >> 1) * 2176 + lane * 34;
#pragma unroll
    for (int dt = 0; dt < 2; ++dt)
#pragma unroll
      for (int r = 0; r < 16; ++r) mb[dt * 16 + r] = acc[dt][r];
    mb[32] = m_r;
    mb[33] = l_r;
  }
  __syncthreads();
  if (!(wid & 1)) {
    const float* mb = fs + (wid >> 1) * 2176 + lane * 34;
    float m1 = mb[32], l1 = mb[33];
    float ms = fmaxf(m_r, m1);
    float e0 = fexp2(m_r - ms), e1 = fexp2(m1 - ms);
    l_r = l_r * e0 + l1 * e1;
#pragma unroll
    for (int dt = 0; dt < 2; ++dt)
#pragma unroll
      for (int r = 0; r < 16; ++r)
        acc[dt][r] = acc[dt][r] * e0 + mb[dt * 16 + r] * e1;

    // O^T regs -> per-tile LDS transpose scratch (beyond the merge area)
    const float l_tot = l_r + __shfl_xor(l_r, 32, 64);
    const float inv = 1.0f / l_tot;
    bf16* scr = smem + 10240 + (wid >> 1) * 2176;   // byte 20480+, 4.25KB each
#pragma unroll
    for (int dt = 0; dt < 2; ++dt)
#pragma unroll
      for (int g2 = 0; g2 < 4; ++g2) {
        union { u16 hh[4]; unsigned long long q8; } pk4;
#pragma unroll
        for (int j = 0; j < 4; ++j) pk4.hh[j] = f2b(acc[dt][g2 * 4 + j] * inv);
        *(unsigned long long*)(scr + l31 * 68 + dt * 32 + g2 * 8 + 4 * hi) = pk4.q8;
      }
  }
  __syncthreads();   // scratch visible for cross-lane reads
  if (!(wid & 1)) {
    const bf16* scr = smem + 10240 + (wid >> 1) * 2176;
    const int qe = lane >> 1, he = lane & 1;
    u16* cp = (u16*)ctx + (long)(q0w + qe) * DMODEL + h * HD + he * 32;
#pragma unroll
    for (int j = 0; j < 4; ++j) {
      u16x8 v = *(const u16x8*)(scr + qe * 68 + he * 32 + j * 8);
      *(u16x8*)(cp + j * 8) = v;
    }
  }
}

extern "C" void kernel_launch(void* const* d_in, const int* in_sizes, int n_in,
                              void* d_out, int out_size, void* d_ws, size_t ws_size,
                              hipStream_t stream) {
  (void)in_sizes; (void)n_in; (void)out_size; (void)ws_size;
  const float* x  = (const float*)d_in[0];
  const float* Wq = (const float*)d_in[1];
  const float* Wk = (const float*)d_in[2];
  const float* Wv = (const float*)d_in[3];
  const float* Wo = (const float*)d_in[4];
  const float* bo = (const float*)d_in[5];
  float* out = (float*)d_out;

  char* ws = (char*)d_ws;
  bf16* xb  = (bf16*)(ws);                    //  8 MB: x bf16 [4096,1024]
  bf16* wqk = (bf16*)(ws + 8388608);          //  4 MB: Wq;Wk [2048,1024]
  bf16* wvb = (bf16*)(ws + 12582912);         //  2 MB: Wv [1024,1024]
  bf16* wob = (bf16*)(ws + 14680064);         //  2 MB: Wo [1024,1024]
  bf16* qkb = (bf16*)(ws + 16777216);         // 16 MB: QK [4096,2048]
  bf16* vtb = (bf16*)(ws + 33554432);         //  8 MB: V^T [1024,4096]
  bf16* ctxb = (bf16*)(ws + 41943040);        //  8 MB: ctx [4096,1024]

  cvt_kernel<<<dim3(4096), dim3(256), 0, stream>>>(x, xb, 4194304);
  cvt_kernel<<<dim3(1024), dim3(256), 0, stream>>>(Wq, wqk, 1048576);
  cvt_kernel<<<dim3(1024), dim3(256), 0, stream>>>(Wk, wqk + 1048576, 1048576);
  cvt_kernel<<<dim3(1024), dim3(256), 0, stream>>>(Wv, wvb, 1048576);
  cvt_kernel<<<dim3(1024), dim3(256), 0, stream>>>(Wo, wob, 1048576);

  // QK = x * [Wq;Wk]^T   -> [4096, 2048]
  gemm_bt<1><<<dim3(16, 32), dim3(256), 0, stream>>>(xb, wqk, (void*)qkb, nullptr,
                                                     4096, 2048, 1024);
  // V^T = Wv * x^T       -> [1024, 4096]   (free transpose via NT GEMM)
  gemm_bt<1><<<dim3(32, 8), dim3(256), 0, stream>>>(wvb, xb, (void*)vtb, nullptr,
                                                    1024, 4096, 1024);
  rope_kernel<<<dim3(16384), dim3(256), 0, stream>>>(qkb);
  attn_kernel<<<dim3(1024), dim3(256), 0, stream>>>(qkb, vtb, ctxb);
  gemm_bt<0><<<dim3(8, 32), dim3(256), 0, stream>>>(ctxb, wob, (void*)out, bo,
                                                    4096, 1024, 1024);
}

// Round 17
// 156.369 us; speedup vs baseline: 1.2202x; 1.2202x over previous
//
#include <hip/hip_runtime.h>
#include <hip/hip_bf16.h>

typedef __hip_bfloat16 bf16;
typedef unsigned short u16;
typedef unsigned int u32;
typedef float f32x4 __attribute__((ext_vector_type(4)));
typedef float f32x16 __attribute__((ext_vector_type(16)));
typedef __bf16 bf16x8 __attribute__((ext_vector_type(8)));
typedef u16 u16x8 __attribute__((ext_vector_type(8)));

#define DMODEL 1024
#define NH 16
#define HD 64
#define QK_LD 2048
#define SLEN 4096

typedef __attribute__((address_space(1))) const void* as1_cvp;
typedef __attribute__((address_space(3))) void* as3_vp;

__device__ __forceinline__ void gload_lds16(const void* g, void* l) {
  __builtin_amdgcn_global_load_lds((as1_cvp)g, (as3_vp)l, 16, 0, 0);
}

__device__ __forceinline__ f32x4 mfma16(bf16x8 a, bf16x8 b, f32x4 c) {
  return __builtin_amdgcn_mfma_f32_16x16x32_bf16(a, b, c, 0, 0, 0);
}
__device__ __forceinline__ f32x16 mfma32(bf16x8 a, bf16x8 b, f32x16 c) {
  return __builtin_amdgcn_mfma_f32_32x32x16_bf16(a, b, c, 0, 0, 0);
}

// raw hardware exp2 (v_exp_f32), no denormal-guard expansion
__device__ __forceinline__ float fexp2(float x) {
#if __has_builtin(__builtin_amdgcn_exp2f)
  return __builtin_amdgcn_exp2f(x);
#else
  return __expf(x * 0.6931471805599453f);
#endif
}

__device__ __forceinline__ u16 f2b(float f) {
  union { bf16 b; u16 s; } u; u.b = __float2bfloat16(f); return u.s;
}
__device__ __forceinline__ u32 pkbf(float a, float b) {
  union { __hip_bfloat162 h; u32 u; } cv;
  cv.h = __float22bfloat162_rn(make_float2(a, b));
  return cv.u;
}

// ------------- fused fp32->bf16 conversion for all 5 inputs -------------
// blocks 0..4095: x (4M elems); then 1024 blocks each: Wq, Wk, Wv, Wo.
__global__ __launch_bounds__(256) void cvt5_kernel(const float* __restrict__ x,
                                                   const float* __restrict__ wq,
                                                   const float* __restrict__ wk,
                                                   const float* __restrict__ wv,
                                                   const float* __restrict__ wo,
                                                   bf16* __restrict__ xb,
                                                   bf16* __restrict__ wqk,
                                                   bf16* __restrict__ wvb,
                                                   bf16* __restrict__ wob) {
  int bid = blockIdx.x;
  const float* src; bf16* dst; long off;
  if (bid < 4096) {
    src = x; dst = xb; off = (long)bid * 1024;
  } else {
    int w = (bid - 4096) >> 10;
    off = (long)((bid - 4096) & 1023) * 1024;
    if (w == 0)      { src = wq; dst = wqk; }
    else if (w == 1) { src = wk; dst = wqk + 1048576; }
    else if (w == 2) { src = wv; dst = wvb; }
    else             { src = wo; dst = wob; }
  }
  long i = off + threadIdx.x * 4;
  float4 v = *(const float4*)(src + i);
  union { ushort4 u; bf16 h[4]; } o;
  o.h[0] = __float2bfloat16(v.x);
  o.h[1] = __float2bfloat16(v.y);
  o.h[2] = __float2bfloat16(v.z);
  o.h[3] = __float2bfloat16(v.w);
  *(ushort4*)(dst + i) = o.u;
}

// ------------- RoPE trig table: tab[s*32+i] = (cos, sin)(s * invf_i) ------
// 131k entries; powf+sincosf kept for numerics identical to prior rounds.
__global__ __launch_bounds__(256) void trig_kernel(float2* __restrict__ tab) {
  int idx = blockIdx.x * 256 + threadIdx.x;   // 0..131071
  int s = idx >> 5, i = idx & 31;
  float invf = powf(10000.0f, -(float)(2 * i) / 64.0f);
  float ang = (float)s * invf;
  float sn, cs;
  sincosf(ang, &sn, &cs);
  tab[idx] = make_float2(cs, sn);
}

// ------------- RoPE on QK [4096][2048], vectorized 8 elems/thread --------
// Q region (col<1024) also scaled by 0.125*log2(e) -> scores in log2 domain.
__global__ __launch_bounds__(256) void rope_kernel(bf16* __restrict__ qk,
                                                   const float2* __restrict__ tab) {
  long e = (long)(blockIdx.x * 256 + threadIdx.x) * 8;   // 8.4M elems total
  int s = (int)(e >> 11);
  int col = (int)(e & 2047);
  int i0 = (col & 63) >> 1;            // pair base within head (aligned to 4)
  float scale = (col < 1024) ? 0.18033688011112042f : 1.0f;
  u16x8 v = *(const u16x8*)((const u16*)qk + e);
  const float4* tp = (const float4*)(tab + s * 32 + i0);  // 2x float4 = 4 pairs
  float4 t0 = tp[0], t1 = tp[1];
  float cs[4] = {t0.x, t0.z, t1.x, t1.z};
  float sn[4] = {t0.y, t0.w, t1.y, t1.w};
  u16x8 o;
#pragma unroll
  for (int j = 0; j < 4; ++j) {
    union { u16 s; bf16 b; } a1, a2;
    a1.s = v[2 * j]; a2.s = v[2 * j + 1];
    float x1 = __bfloat162float(a1.b);
    float x2 = __bfloat162float(a2.b);
    o[2 * j]     = f2b((x1 * cs[j] - x2 * sn[j]) * scale);
    o[2 * j + 1] = f2b((x1 * sn[j] + x2 * cs[j]) * scale);
  }
  *(u16x8*)((u16*)qk + e) = o;
}

// ---------------- NT GEMM: C[M,N] = A[M,K] * B[N,K]^T ----------------
template <int OUT_BF16>
__global__ __launch_bounds__(256) void gemm_bt(const bf16* __restrict__ A,
                                               const bf16* __restrict__ B,
                                               void* __restrict__ Cout,
                                               const float* __restrict__ bias,
                                               int M, int N, int K) {
  __shared__ __align__(16) bf16 As[128 * 32];
  __shared__ __align__(16) bf16 Bs[128 * 32];
  const int tid = threadIdx.x;
  const int lane = tid & 63;
  const int wid = tid >> 6;
  const int brow = blockIdx.y * 128;
  const int bcol = blockIdx.x * 128;
  const int wr = wid >> 1, wc = wid & 1;

  f32x4 acc[4][4] = {};

  const int srow = lane >> 2;
  const int scol = (lane & 3) * 8;
  const bf16* Ag = A + (long)(brow + wid * 32 + srow) * K + scol;
  const bf16* Bg = B + (long)(bcol + wid * 32 + srow) * K + scol;
  bf16* AsW = As + wid * 32 * 32;
  bf16* BsW = Bs + wid * 32 * 32;
  const int kof = (lane >> 4) * 8;
  const int r16 = lane & 15;

  for (int k0 = 0; k0 < K; k0 += 32) {
    __syncthreads();
    gload_lds16(Ag + k0, AsW);
    gload_lds16(Ag + k0 + (long)16 * K, AsW + 16 * 32);
    gload_lds16(Bg + k0, BsW);
    gload_lds16(Bg + k0 + (long)16 * K, BsW + 16 * 32);
    __syncthreads();
    bf16x8 af[4], bfr[4];
#pragma unroll
    for (int m = 0; m < 4; ++m)
      af[m] = *(const bf16x8*)(As + (wr * 64 + m * 16 + r16) * 32 + kof);
#pragma unroll
    for (int n = 0; n < 4; ++n)
      bfr[n] = *(const bf16x8*)(Bs + (wc * 64 + n * 16 + r16) * 32 + kof);
#pragma unroll
    for (int m = 0; m < 4; ++m)
#pragma unroll
      for (int n = 0; n < 4; ++n)
        acc[m][n] = mfma16(af[m], bfr[n], acc[m][n]);
  }

  const int r0 = (lane >> 4) * 4;
#pragma unroll
  for (int m = 0; m < 4; ++m) {
#pragma unroll
    for (int n = 0; n < 4; ++n) {
      int row = brow + wr * 64 + m * 16 + r0;
      int col = bcol + wc * 64 + n * 16 + r16;
#pragma unroll
      for (int r = 0; r < 4; ++r) {
        if (OUT_BF16) {
          ((bf16*)Cout)[(long)(row + r) * N + col] = __float2bfloat16(acc[m][n][r]);
        } else {
          ((float*)Cout)[(long)(row + r) * N + col] = acc[m][n][r] + bias[col];
        }
      }
    }
  }
}

// ------------- fused QK + V^T GEMM (one launch, block-id dispatch) -------
// blocks 0..511:  QK  = xb  * wqk^T -> qkb [4096,2048]
// blocks 512..767: V^T = wvb * xb^T  -> vtb [1024,4096]
__global__ __launch_bounds__(256) void gemm_qkv(const bf16* __restrict__ xb,
                                                const bf16* __restrict__ wqk,
                                                const bf16* __restrict__ wvb,
                                                bf16* __restrict__ qkb,
                                                bf16* __restrict__ vtb) {
  const int bid = blockIdx.x;
  const bf16 *A, *B;
  bf16* C;
  int N, bx, by;
  if (bid < 512) { A = xb;  B = wqk; C = qkb; N = 2048; bx = bid & 15; by = bid >> 4; }
  else { int r = bid - 512; A = wvb; B = xb;  C = vtb; N = 4096; bx = r & 31; by = r >> 5; }
  const int K = 1024;

  __shared__ __align__(16) bf16 As[128 * 32];
  __shared__ __align__(16) bf16 Bs[128 * 32];
  const int tid = threadIdx.x;
  const int lane = tid & 63;
  const int wid = tid >> 6;
  const int brow = by * 128;
  const int bcol = bx * 128;
  const int wr = wid >> 1, wc = wid & 1;

  f32x4 acc[4][4] = {};

  const int srow = lane >> 2;
  const int scol = (lane & 3) * 8;
  const bf16* Ag = A + (long)(brow + wid * 32 + srow) * K + scol;
  const bf16* Bg = B + (long)(bcol + wid * 32 + srow) * K + scol;
  bf16* AsW = As + wid * 32 * 32;
  bf16* BsW = Bs + wid * 32 * 32;
  const int kof = (lane >> 4) * 8;
  const int r16 = lane & 15;

  for (int k0 = 0; k0 < K; k0 += 32) {
    __syncthreads();
    gload_lds16(Ag + k0, AsW);
    gload_lds16(Ag + k0 + (long)16 * K, AsW + 16 * 32);
    gload_lds16(Bg + k0, BsW);
    gload_lds16(Bg + k0 + (long)16 * K, BsW + 16 * 32);
    __syncthreads();
    bf16x8 af[4], bfr[4];
#pragma unroll
    for (int m = 0; m < 4; ++m)
      af[m] = *(const bf16x8*)(As + (wr * 64 + m * 16 + r16) * 32 + kof);
#pragma unroll
    for (int n = 0; n < 4; ++n)
      bfr[n] = *(const bf16x8*)(Bs + (wc * 64 + n * 16 + r16) * 32 + kof);
#pragma unroll
    for (int m = 0; m < 4; ++m)
#pragma unroll
      for (int n = 0; n < 4; ++n)
        acc[m][n] = mfma16(af[m], bfr[n], acc[m][n]);
  }

  const int r0 = (lane >> 4) * 4;
#pragma unroll
  for (int m = 0; m < 4; ++m) {
#pragma unroll
    for (int n = 0; n < 4; ++n) {
      int row = brow + wr * 64 + m * 16 + r0;
      int col = bcol + wc * 64 + n * 16 + r16;
#pragma unroll
      for (int r = 0; r < 4; ++r)
        C[(long)(row + r) * N + col] = __float2bfloat16(acc[m][n][r]);
    }
  }
}

// ---------------- causal flash attention (v13 — unchanged) ----------------
__global__ __launch_bounds__(256, 4) void attn_kernel(const bf16* __restrict__ qk,
                                                      const bf16* __restrict__ vt,
                                                      bf16* __restrict__ ctx) {
  __shared__ __align__(16) bf16 smem[16384];   // 32 KB
  bf16 (*Ks)[64][64] = (bf16(*)[64][64])(smem);          // 2 bufs, [kv][d]
  bf16 (*Vt)[64][64] = (bf16(*)[64][64])(smem + 8192);   // 2 bufs, [d][kv]

  const int tid = threadIdx.x;
  const int lane = tid & 63;
  const int wid = tid >> 6;            // 0..3
  const int hi = lane >> 5;
  const int l31 = lane & 31;
  const int t = blockIdx.x >> 4;       // 0..63
  const int h = blockIdx.x & 15;
  const int p = wid & 1;               // kv-half parity within the tile pair
  const int qblk = (wid < 2) ? (127 - t) : t;   // 32-row q tile
  const int q0w = qblk * 32;
  const long kcol = DMODEL + (long)h * HD;      // K region in qk rows

  // Q B-fragments: lane holds Q[q=l31][d = kt*16 + hi*8 .. +8]
  bf16x8 qf[4];
  {
    const bf16* qp = qk + (long)(q0w + l31) * QK_LD + h * HD + hi * 8;
#pragma unroll
    for (int kt = 0; kt < 4; ++kt) qf[kt] = *(const bf16x8*)(qp + kt * 16);
  }

  const int kOff = ((lane & 7) ^ (lane >> 3)) * 8;   // pre-swizzled src slot
  const int lr = lane >> 3;
  const int srowp = (lr & 3) + 8 * (lr >> 2);        // sigma base for K rows

  // hoisted swizzled LDS element offsets
  int kro[4];
#pragma unroll
  for (int kt = 0; kt < 4; ++kt)
    kro[kt] = l31 * 64 + ((((kt << 1) | hi) ^ (l31 & 7)) * 8);
  const int vbase = l31 * 64;
  const int vslotx = l31 & 7;

  // V^T source rows for this block's head
  const bf16* vth = vt + (long)h * HD * SLEN;

  f32x16 acc[2] = {};
  float m_r = -1e30f, l_r = 0.0f;      // own-lane online-softmax state

  const int nkb = (129 - t) >> 1;      // 64-row KV blocks covering heavy tile
  const int vR = lane >> 3;            // V stage: row within 8-row chunk

  // prologue: stage KV block 0 into buf 0 (K sigma rows; V^T rows direct)
  {
#pragma unroll
    for (int c2 = 0; c2 < 2; ++c2) {
      const int c = wid * 2 + c2;
      const int sub = c >> 2, cc = c & 3;
      gload_lds16(qk + (long)(sub * 32 + srowp + 4 * (cc & 1) + 16 * (cc >> 1)) * QK_LD + kcol + kOff,
                  &Ks[0][c * 8][0]);
    }
#pragma unroll
    for (int c2 = 0; c2 < 2; ++c2) {
      const int d0 = wid * 16 + c2 * 8;
      gload_lds16(vth + (long)(d0 + vR) * SLEN + kOff, &Vt[0][d0][0]);
    }
  }

  for (int kb = 0; kb < nkb; ++kb) {
    const int cur = kb & 1;
    const int kvs = kb * 64 + p * 32;   // this wave's sub
    const bool pre = (kb + 1 < nkb);
    __syncthreads();   // staging of block kb visible; prev iter reads done

    // prefetch next KV block into the other buffer (async, no reg staging)
    if (pre) {
      const long kvn = (long)(kb + 1) * 64;
#pragma unroll
      for (int c2 = 0; c2 < 2; ++c2) {
        const int c = wid * 2 + c2;
        const int sub = c >> 2, cc = c & 3;
        gload_lds16(qk + (kvn + sub * 32 + srowp + 4 * (cc & 1) + 16 * (cc >> 1)) * QK_LD + kcol + kOff,
                    &Ks[cur ^ 1][c * 8][0]);
      }
#pragma unroll
      for (int c2 = 0; c2 < 2; ++c2) {
        const int d0 = wid * 16 + c2 * 8;
        gload_lds16(vth + (long)(d0 + vR) * SLEN + kvn + kOff, &Vt[cur ^ 1][d0][0]);
      }
    }

    if (kvs <= q0w + 31) {   // wave-uniform activity test
      const bf16* KsC = &Ks[cur][0][0];
      const bf16* VtC = &Vt[cur][0][0];

      // S^T = K * Q^T over d=64 (4 mfma of k=16) on this wave's sub
      f32x16 c16 = {};
      __builtin_amdgcn_s_setprio(1);
#pragma unroll
      for (int kt = 0; kt < 4; ++kt) {
        bf16x8 kf = *(const bf16x8*)(KsC + p * 2048 + kro[kt]);
        c16 = mfma32(kf, qf[kt], c16);
      }
      __builtin_amdgcn_s_setprio(0);

      // causal mask; kv of reg r under sigma:
      // kv = kvs + (r&3) + 4*((r>>2)&1) + 8*hi + 16*(r>>3)
      if (kvs + 31 > q0w) {
        const int q = q0w + l31;
        const int kvb = kvs + 8 * hi;
#pragma unroll
        for (int r = 0; r < 16; ++r) {
          int kv = kvb + (r & 3) + 4 * ((r >> 2) & 1) + 16 * (r >> 3);
          if (kv > q) c16[r] = -1e30f;
        }
      }

      // per-lane online softmax; pair (l, l^32) holds the 32 kv of this sub
      float x0 = fmaxf(fmaxf(c16[0], c16[1]), fmaxf(c16[2], c16[3]));
      float x1 = fmaxf(fmaxf(c16[4], c16[5]), fmaxf(c16[6], c16[7]));
      float x2 = fmaxf(fmaxf(c16[8], c16[9]), fmaxf(c16[10], c16[11]));
      float x3 = fmaxf(fmaxf(c16[12], c16[13]), fmaxf(c16[14], c16[15]));
      float pmax = fmaxf(fmaxf(x0, x1), fmaxf(x2, x3));
      pmax = fmaxf(pmax, __shfl_xor(pmax, 32, 64));

      if (!__all(pmax <= m_r + 11.0f)) {   // defer-max (log2 units)
        float mn = fmaxf(m_r, pmax);
        float al = fexp2(m_r - mn);
        m_r = mn;
        l_r *= al;
#pragma unroll
        for (int dt = 0; dt < 2; ++dt)
#pragma unroll
          for (int r = 0; r < 16; ++r) acc[dt][r] *= al;
      }

      float pa[16];
#pragma unroll
      for (int r = 0; r < 16; ++r) pa[r] = fexp2(c16[r] - m_r);
      float rs = ((pa[0] + pa[1]) + (pa[2] + pa[3])) + ((pa[4] + pa[5]) + (pa[6] + pa[7])) +
                 (((pa[8] + pa[9]) + (pa[10] + pa[11])) + ((pa[12] + pa[13]) + (pa[14] + pa[15])));
      l_r += rs;

      // P^T -> B-fragments: straight in-order pairwise packs (sigma layout)
      union BP { u32 u[4]; bf16x8 v; } f0, f1;
      f0.u[0] = pkbf(pa[0], pa[1]);   f0.u[1] = pkbf(pa[2], pa[3]);
      f0.u[2] = pkbf(pa[4], pa[5]);   f0.u[3] = pkbf(pa[6], pa[7]);
      f1.u[0] = pkbf(pa[8], pa[9]);   f1.u[1] = pkbf(pa[10], pa[11]);
      f1.u[2] = pkbf(pa[12], pa[13]); f1.u[3] = pkbf(pa[14], pa[15]);

      // O^T += V^T * P^T
      __builtin_amdgcn_s_setprio(1);
#pragma unroll
      for (int dt = 0; dt < 2; ++dt) {
        const bf16* vrow = VtC + dt * 2048 + vbase;
        bf16x8 v0 = *(const bf16x8*)(vrow + (((p * 4 + hi) ^ vslotx) * 8));
        acc[dt] = mfma32(v0, f0.v, acc[dt]);
        bf16x8 v1 = *(const bf16x8*)(vrow + (((p * 4 + 2 + hi) ^ vslotx) * 8));
        acc[dt] = mfma32(v1, f1.v, acc[dt]);
      }
      __builtin_amdgcn_s_setprio(0);
    }
  }

  // ---- split-KV merge: waves (0,1) and (2,3) combine (m, l, acc) ----
  __syncthreads();   // everyone done with Ks/Vt; LDS reused
  float* fs = (float*)smem;          // 2 x 64 x 34 floats = 17.4 KB merge area
  if (wid & 1) {
    float* mb = fs + (wid >> 1) * 2176 + lane * 34;
#pragma unroll
    for (int dt = 0; dt < 2; ++dt)
#pragma unroll
      for (int r = 0; r < 16; ++r) mb[dt * 16 + r] = acc[dt][r];
    mb[32] = m_r;
    mb[33] = l_r;
  }
  __syncthreads();
  if (!(wid & 1)) {
    const float* mb = fs + (wid >> 1) * 2176 + lane * 34;
    float m1 = mb[32], l1 = mb[33];
    float ms = fmaxf(m_r, m1);
    float e0 = fexp2(m_r - ms), e1 = fexp2(m1 - ms);
    l_r = l_r * e0 + l1 * e1;
#pragma unroll
    for (int dt = 0; dt < 2; ++dt)
#pragma unroll
      for (int r = 0; r < 16; ++r)
        acc[dt][r] = acc[dt][r] * e0 + mb[dt * 16 + r] * e1;

    // O^T regs -> per-tile LDS transpose scratch (beyond the merge area)
    const float l_tot = l_r + __shfl_xor(l_r, 32, 64);
    const float inv = 1.0f / l_tot;
    bf16* scr = smem + 10240 + (wid >> 1) * 2176;   // byte 20480+, 4.25KB each
#pragma unroll
    for (int dt = 0; dt < 2; ++dt)
#pragma unroll
      for (int g2 = 0; g2 < 4; ++g2) {
        union { u16 hh[4]; unsigned long long q8; } pk4;
#pragma unroll
        for (int j = 0; j < 4; ++j) pk4.hh[j] = f2b(acc[dt][g2 * 4 + j] * inv);
        *(unsigned long long*)(scr + l31 * 68 + dt * 32 + g2 * 8 + 4 * hi) = pk4.q8;
      }
  }
  __syncthreads();   // scratch visible for cross-lane reads
  if (!(wid & 1)) {
    const bf16* scr = smem + 10240 + (wid >> 1) * 2176;
    const int qe = lane >> 1, he = lane & 1;
    u16* cp = (u16*)ctx + (long)(q0w + qe) * DMODEL + h * HD + he * 32;
#pragma unroll
    for (int j = 0; j < 4; ++j) {
      u16x8 v = *(const u16x8*)(scr + qe * 68 + he * 32 + j * 8);
      *(u16x8*)(cp + j * 8) = v;
    }
  }
}

extern "C" void kernel_launch(void* const* d_in, const int* in_sizes, int n_in,
                              void* d_out, int out_size, void* d_ws, size_t ws_size,
                              hipStream_t stream) {
  (void)in_sizes; (void)n_in; (void)out_size; (void)ws_size;
  const float* x  = (const float*)d_in[0];
  const float* Wq = (const float*)d_in[1];
  const float* Wk = (const float*)d_in[2];
  const float* Wv = (const float*)d_in[3];
  const float* Wo = (const float*)d_in[4];
  const float* bo = (const float*)d_in[5];
  float* out = (float*)d_out;

  char* ws = (char*)d_ws;
  bf16* xb  = (bf16*)(ws);                    //  8 MB: x bf16 [4096,1024]
  bf16* wqk = (bf16*)(ws + 8388608);          //  4 MB: Wq;Wk [2048,1024]
  bf16* wvb = (bf16*)(ws + 12582912);         //  2 MB: Wv [1024,1024]
  bf16* wob = (bf16*)(ws + 14680064);         //  2 MB: Wo [1024,1024]
  bf16* qkb = (bf16*)(ws + 16777216);         // 16 MB: QK [4096,2048]
  bf16* vtb = (bf16*)(ws + 33554432);         //  8 MB: V^T [1024,4096]
  bf16* ctxb = (bf16*)(ws + 41943040);        //  8 MB: ctx [4096,1024]
  float2* tab = (float2*)(ws + 50331648);     //  1 MB: RoPE trig table

  trig_kernel<<<dim3(512), dim3(256), 0, stream>>>(tab);
  cvt5_kernel<<<dim3(8192), dim3(256), 0, stream>>>(x, Wq, Wk, Wv, Wo,
                                                    xb, wqk, wvb, wob);
  gemm_qkv<<<dim3(768), dim3(256), 0, stream>>>(xb, wqk, wvb, qkb, vtb);
  rope_kernel<<<dim3(4096), dim3(256), 0, stream>>>(qkb, tab);
  attn_kernel<<<dim3(1024), dim3(256), 0, stream>>>(qkb, vtb, ctxb);
  gemm_bt<0><<<dim3(8, 32), dim3(256), 0, stream>>>(ctxb, wob, (void*)out, bo,
                                                    4096, 1024, 1024);
}

// Round 19
// 152.609 us; speedup vs baseline: 1.2502x; 1.0246x over previous
//
#include <hip/hip_runtime.h>
#include <hip/hip_bf16.h>

typedef __hip_bfloat16 bf16;
typedef unsigned short u16;
typedef unsigned int u32;
typedef float f32x4 __attribute__((ext_vector_type(4)));
typedef float f32x16 __attribute__((ext_vector_type(16)));
typedef __bf16 bf16x8 __attribute__((ext_vector_type(8)));
typedef u16 u16x8 __attribute__((ext_vector_type(8)));

#define DMODEL 1024
#define NH 16
#define HD 64
#define QK_LD 2048
#define SLEN 4096

typedef __attribute__((address_space(1))) const void* as1_cvp;
typedef __attribute__((address_space(3))) void* as3_vp;

__device__ __forceinline__ void gload_lds16(const void* g, void* l) {
  __builtin_amdgcn_global_load_lds((as1_cvp)g, (as3_vp)l, 16, 0, 0);
}

__device__ __forceinline__ f32x4 mfma16(bf16x8 a, bf16x8 b, f32x4 c) {
  return __builtin_amdgcn_mfma_f32_16x16x32_bf16(a, b, c, 0, 0, 0);
}
__device__ __forceinline__ f32x16 mfma32(bf16x8 a, bf16x8 b, f32x16 c) {
  return __builtin_amdgcn_mfma_f32_32x32x16_bf16(a, b, c, 0, 0, 0);
}

// raw hardware exp2 (v_exp_f32), no denormal-guard expansion
__device__ __forceinline__ float fexp2(float x) {
#if __has_builtin(__builtin_amdgcn_exp2f)
  return __builtin_amdgcn_exp2f(x);
#else
  return __expf(x * 0.6931471805599453f);
#endif
}

__device__ __forceinline__ u16 f2b(float f) {
  union { bf16 b; u16 s; } u; u.b = __float2bfloat16(f); return u.s;
}
__device__ __forceinline__ u32 pkbf(float a, float b) {
  union { __hip_bfloat162 h; u32 u; } cv;
  cv.h = __float22bfloat162_rn(make_float2(a, b));
  return cv.u;
}

// ------- fused fp32->bf16 conversion (5 inputs) + RoPE trig table --------
// blocks 0..4095: x; 4096..8191: Wq/Wk/Wv/Wo (1024 each); 8192..8703: trig.
__global__ __launch_bounds__(256) void cvt5_kernel(const float* __restrict__ x,
                                                   const float* __restrict__ wq,
                                                   const float* __restrict__ wk,
                                                   const float* __restrict__ wv,
                                                   const float* __restrict__ wo,
                                                   bf16* __restrict__ xb,
                                                   bf16* __restrict__ wqk,
                                                   bf16* __restrict__ wvb,
                                                   bf16* __restrict__ wob,
                                                   float2* __restrict__ tab) {
  int bid = blockIdx.x;
  if (bid >= 8192) {   // trig table: tab[s*32+i] = (cos,sin)(s * invf_i)
    int idx = (bid - 8192) * 256 + threadIdx.x;   // 0..131071
    int s = idx >> 5, i = idx & 31;
    float invf = powf(10000.0f, -(float)(2 * i) / 64.0f);
    float ang = (float)s * invf;
    float sn, cs;
    sincosf(ang, &sn, &cs);
    tab[idx] = make_float2(cs, sn);
    return;
  }
  const float* src; bf16* dst; long off;
  if (bid < 4096) {
    src = x; dst = xb; off = (long)bid * 1024;
  } else {
    int w = (bid - 4096) >> 10;
    off = (long)((bid - 4096) & 1023) * 1024;
    if (w == 0)      { src = wq; dst = wqk; }
    else if (w == 1) { src = wk; dst = wqk + 1048576; }
    else if (w == 2) { src = wv; dst = wvb; }
    else             { src = wo; dst = wob; }
  }
  long i = off + threadIdx.x * 4;
  float4 v = *(const float4*)(src + i);
  union { ushort4 u; bf16 h[4]; } o;
  o.h[0] = __float2bfloat16(v.x);
  o.h[1] = __float2bfloat16(v.y);
  o.h[2] = __float2bfloat16(v.z);
  o.h[3] = __float2bfloat16(v.w);
  *(ushort4*)(dst + i) = o.u;
}

// ------------- RoPE on QK [4096][2048], vectorized 8 elems/thread --------
__global__ __launch_bounds__(256) void rope_kernel(bf16* __restrict__ qk,
                                                   const float2* __restrict__ tab) {
  long e = (long)(blockIdx.x * 256 + threadIdx.x) * 8;
  int s = (int)(e >> 11);
  int col = (int)(e & 2047);
  int i0 = (col & 63) >> 1;
  float scale = (col < 1024) ? 0.18033688011112042f : 1.0f;
  u16x8 v = *(const u16x8*)((const u16*)qk + e);
  const float4* tp = (const float4*)(tab + s * 32 + i0);
  float4 t0 = tp[0], t1 = tp[1];
  float cs[4] = {t0.x, t0.z, t1.x, t1.z};
  float sn[4] = {t0.y, t0.w, t1.y, t1.w};
  u16x8 o;
#pragma unroll
  for (int j = 0; j < 4; ++j) {
    union { u16 s; bf16 b; } a1, a2;
    a1.s = v[2 * j]; a2.s = v[2 * j + 1];
    float x1 = __bfloat162float(a1.b);
    float x2 = __bfloat162float(a2.b);
    o[2 * j]     = f2b((x1 * cs[j] - x2 * sn[j]) * scale);
    o[2 * j + 1] = f2b((x1 * sn[j] + x2 * cs[j]) * scale);
  }
  *(u16x8*)((u16*)qk + e) = o;
}

// ---------------- NT GEMM: C[M,N] = A[M,K] * B[N,K]^T ----------------
template <int OUT_BF16>
__global__ __launch_bounds__(256) void gemm_bt(const bf16* __restrict__ A,
                                               const bf16* __restrict__ B,
                                               void* __restrict__ Cout,
                                               const float* __restrict__ bias,
                                               int M, int N, int K) {
  __shared__ __align__(16) bf16 As[128 * 32];
  __shared__ __align__(16) bf16 Bs[128 * 32];
  const int tid = threadIdx.x;
  const int lane = tid & 63;
  const int wid = tid >> 6;
  const int brow = blockIdx.y * 128;
  const int bcol = blockIdx.x * 128;
  const int wr = wid >> 1, wc = wid & 1;

  f32x4 acc[4][4] = {};

  const int srow = lane >> 2;
  const int scol = (lane & 3) * 8;
  const bf16* Ag = A + (long)(brow + wid * 32 + srow) * K + scol;
  const bf16* Bg = B + (long)(bcol + wid * 32 + srow) * K + scol;
  bf16* AsW = As + wid * 32 * 32;
  bf16* BsW = Bs + wid * 32 * 32;
  const int kof = (lane >> 4) * 8;
  const int r16 = lane & 15;

  for (int k0 = 0; k0 < K; k0 += 32) {
    __syncthreads();
    gload_lds16(Ag + k0, AsW);
    gload_lds16(Ag + k0 + (long)16 * K, AsW + 16 * 32);
    gload_lds16(Bg + k0, BsW);
    gload_lds16(Bg + k0 + (long)16 * K, BsW + 16 * 32);
    __syncthreads();
    bf16x8 af[4], bfr[4];
#pragma unroll
    for (int m = 0; m < 4; ++m)
      af[m] = *(const bf16x8*)(As + (wr * 64 + m * 16 + r16) * 32 + kof);
#pragma unroll
    for (int n = 0; n < 4; ++n)
      bfr[n] = *(const bf16x8*)(Bs + (wc * 64 + n * 16 + r16) * 32 + kof);
#pragma unroll
    for (int m = 0; m < 4; ++m)
#pragma unroll
      for (int n = 0; n < 4; ++n)
        acc[m][n] = mfma16(af[m], bfr[n], acc[m][n]);
  }

  const int r0 = (lane >> 4) * 4;
#pragma unroll
  for (int m = 0; m < 4; ++m) {
#pragma unroll
    for (int n = 0; n < 4; ++n) {
      int row = brow + wr * 64 + m * 16 + r0;
      int col = bcol + wc * 64 + n * 16 + r16;
#pragma unroll
      for (int r = 0; r < 4; ++r) {
        if (OUT_BF16) {
          ((bf16*)Cout)[(long)(row + r) * N + col] = __float2bfloat16(acc[m][n][r]);
        } else {
          ((float*)Cout)[(long)(row + r) * N + col] = acc[m][n][r] + bias[col];
        }
      }
    }
  }
}

// ------------- fused QK + V^T GEMM (one launch, block-id dispatch) -------
__global__ __launch_bounds__(256) void gemm_qkv(const bf16* __restrict__ xb,
                                                const bf16* __restrict__ wqk,
                                                const bf16* __restrict__ wvb,
                                                bf16* __restrict__ qkb,
                                                bf16* __restrict__ vtb) {
  const int bid = blockIdx.x;
  const bf16 *A, *B;
  bf16* C;
  int N, bx, by;
  if (bid < 512) { A = xb;  B = wqk; C = qkb; N = 2048; bx = bid & 15; by = bid >> 4; }
  else { int r = bid - 512; A = wvb; B = xb;  C = vtb; N = 4096; bx = r & 31; by = r >> 5; }
  const int K = 1024;

  __shared__ __align__(16) bf16 As[128 * 32];
  __shared__ __align__(16) bf16 Bs[128 * 32];
  const int tid = threadIdx.x;
  const int lane = tid & 63;
  const int wid = tid >> 6;
  const int brow = by * 128;
  const int bcol = bx * 128;
  const int wr = wid >> 1, wc = wid & 1;

  f32x4 acc[4][4] = {};

  const int srow = lane >> 2;
  const int scol = (lane & 3) * 8;
  const bf16* Ag = A + (long)(brow + wid * 32 + srow) * K + scol;
  const bf16* Bg = B + (long)(bcol + wid * 32 + srow) * K + scol;
  bf16* AsW = As + wid * 32 * 32;
  bf16* BsW = Bs + wid * 32 * 32;
  const int kof = (lane >> 4) * 8;
  const int r16 = lane & 15;

  for (int k0 = 0; k0 < K; k0 += 32) {
    __syncthreads();
    gload_lds16(Ag + k0, AsW);
    gload_lds16(Ag + k0 + (long)16 * K, AsW + 16 * 32);
    gload_lds16(Bg + k0, BsW);
    gload_lds16(Bg + k0 + (long)16 * K, BsW + 16 * 32);
    __syncthreads();
    bf16x8 af[4], bfr[4];
#pragma unroll
    for (int m = 0; m < 4; ++m)
      af[m] = *(const bf16x8*)(As + (wr * 64 + m * 16 + r16) * 32 + kof);
#pragma unroll
    for (int n = 0; n < 4; ++n)
      bfr[n] = *(const bf16x8*)(Bs + (wc * 64 + n * 16 + r16) * 32 + kof);
#pragma unroll
    for (int m = 0; m < 4; ++m)
#pragma unroll
      for (int n = 0; n < 4; ++n)
        acc[m][n] = mfma16(af[m], bfr[n], acc[m][n]);
  }

  const int r0 = (lane >> 4) * 4;
#pragma unroll
  for (int m = 0; m < 4; ++m) {
#pragma unroll
    for (int n = 0; n < 4; ++n) {
      int row = brow + wr * 64 + m * 16 + r0;
      int col = bcol + wc * 64 + n * 16 + r16;
#pragma unroll
      for (int r = 0; r < 4; ++r)
        C[(long)(row + r) * N + col] = __float2bfloat16(acc[m][n][r]);
    }
  }
}

// ---------------- causal flash attention (v13 — R17-proven, reverted) ------
// v14's single-tile remap REFUTED (R18: absmax 0.092, bug not isolable).
__global__ __launch_bounds__(256, 4) void attn_kernel(const bf16* __restrict__ qk,
                                                      const bf16* __restrict__ vt,
                                                      bf16* __restrict__ ctx) {
  __shared__ __align__(16) bf16 smem[16384];   // 32 KB
  bf16 (*Ks)[64][64] = (bf16(*)[64][64])(smem);          // 2 bufs, [kv][d]
  bf16 (*Vt)[64][64] = (bf16(*)[64][64])(smem + 8192);   // 2 bufs, [d][kv]

  const int tid = threadIdx.x;
  const int lane = tid & 63;
  const int wid = tid >> 6;            // 0..3
  const int hi = lane >> 5;
  const int l31 = lane & 31;
  const int t = blockIdx.x >> 4;       // 0..63
  const int h = blockIdx.x & 15;
  const int p = wid & 1;               // kv-half parity within the tile pair
  const int qblk = (wid < 2) ? (127 - t) : t;   // 32-row q tile
  const int q0w = qblk * 32;
  const long kcol = DMODEL + (long)h * HD;      // K region in qk rows

  // Q B-fragments: lane holds Q[q=l31][d = kt*16 + hi*8 .. +8]
  bf16x8 qf[4];
  {
    const bf16* qp = qk + (long)(q0w + l31) * QK_LD + h * HD + hi * 8;
#pragma unroll
    for (int kt = 0; kt < 4; ++kt) qf[kt] = *(const bf16x8*)(qp + kt * 16);
  }

  const int kOff = ((lane & 7) ^ (lane >> 3)) * 8;   // pre-swizzled src slot
  const int lr = lane >> 3;
  const int srowp = (lr & 3) + 8 * (lr >> 2);        // sigma base for K rows

  // hoisted swizzled LDS element offsets
  int kro[4];
#pragma unroll
  for (int kt = 0; kt < 4; ++kt)
    kro[kt] = l31 * 64 + ((((kt << 1) | hi) ^ (l31 & 7)) * 8);
  const int vbase = l31 * 64;
  const int vslotx = l31 & 7;

  // V^T source rows for this block's head
  const bf16* vth = vt + (long)h * HD * SLEN;

  f32x16 acc[2] = {};
  float m_r = -1e30f, l_r = 0.0f;      // own-lane online-softmax state

  const int nkb = (129 - t) >> 1;      // 64-row KV blocks covering heavy tile
  const int vR = lane >> 3;            // V stage: row within 8-row chunk

  // prologue: stage KV block 0 into buf 0 (K sigma rows; V^T rows direct)
  {
#pragma unroll
    for (int c2 = 0; c2 < 2; ++c2) {
      const int c = wid * 2 + c2;
      const int sub = c >> 2, cc = c & 3;
      gload_lds16(qk + (long)(sub * 32 + srowp + 4 * (cc & 1) + 16 * (cc >> 1)) * QK_LD + kcol + kOff,
                  &Ks[0][c * 8][0]);
    }
#pragma unroll
    for (int c2 = 0; c2 < 2; ++c2) {
      const int d0 = wid * 16 + c2 * 8;
      gload_lds16(vth + (long)(d0 + vR) * SLEN + kOff, &Vt[0][d0][0]);
    }
  }

  for (int kb = 0; kb < nkb; ++kb) {
    const int cur = kb & 1;
    const int kvs = kb * 64 + p * 32;   // this wave's sub
    const bool pre = (kb + 1 < nkb);
    __syncthreads();   // staging of block kb visible; prev iter reads done

    // prefetch next KV block into the other buffer (async, no reg staging)
    if (pre) {
      const long kvn = (long)(kb + 1) * 64;
#pragma unroll
      for (int c2 = 0; c2 < 2; ++c2) {
        const int c = wid * 2 + c2;
        const int sub = c >> 2, cc = c & 3;
        gload_lds16(qk + (kvn + sub * 32 + srowp + 4 * (cc & 1) + 16 * (cc >> 1)) * QK_LD + kcol + kOff,
                    &Ks[cur ^ 1][c * 8][0]);
      }
#pragma unroll
      for (int c2 = 0; c2 < 2; ++c2) {
        const int d0 = wid * 16 + c2 * 8;
        gload_lds16(vth + (long)(d0 + vR) * SLEN + kvn + kOff, &Vt[cur ^ 1][d0][0]);
      }
    }

    if (kvs <= q0w + 31) {   // wave-uniform activity test
      const bf16* KsC = &Ks[cur][0][0];
      const bf16* VtC = &Vt[cur][0][0];

      // S^T = K * Q^T over d=64 (4 mfma of k=16) on this wave's sub
      f32x16 c16 = {};
      __builtin_amdgcn_s_setprio(1);
#pragma unroll
      for (int kt = 0; kt < 4; ++kt) {
        bf16x8 kf = *(const bf16x8*)(KsC + p * 2048 + kro[kt]);
        c16 = mfma32(kf, qf[kt], c16);
      }
      __builtin_amdgcn_s_setprio(0);

      // causal mask; kv of reg r under sigma:
      // kv = kvs + (r&3) + 4*((r>>2)&1) + 8*hi + 16*(r>>3)
      if (kvs + 31 > q0w) {
        const int q = q0w + l31;
        const int kvb = kvs + 8 * hi;
#pragma unroll
        for (int r = 0; r < 16; ++r) {
          int kv = kvb + (r & 3) + 4 * ((r >> 2) & 1) + 16 * (r >> 3);
          if (kv > q) c16[r] = -1e30f;
        }
      }

      // per-lane online softmax; pair (l, l^32) holds the 32 kv of this sub
      float x0 = fmaxf(fmaxf(c16[0], c16[1]), fmaxf(c16[2], c16[3]));
      float x1 = fmaxf(fmaxf(c16[4], c16[5]), fmaxf(c16[6], c16[7]));
      float x2 = fmaxf(fmaxf(c16[8], c16[9]), fmaxf(c16[10], c16[11]));
      float x3 = fmaxf(fmaxf(c16[12], c16[13]), fmaxf(c16[14], c16[15]));
      float pmax = fmaxf(fmaxf(x0, x1), fmaxf(x2, x3));
      pmax = fmaxf(pmax, __shfl_xor(pmax, 32, 64));

      if (!__all(pmax <= m_r + 11.0f)) {   // defer-max (log2 units)
        float mn = fmaxf(m_r, pmax);
        float al = fexp2(m_r - mn);
        m_r = mn;
        l_r *= al;
#pragma unroll
        for (int dt = 0; dt < 2; ++dt)
#pragma unroll
          for (int r = 0; r < 16; ++r) acc[dt][r] *= al;
      }

      float pa[16];
#pragma unroll
      for (int r = 0; r < 16; ++r) pa[r] = fexp2(c16[r] - m_r);
      float rs = ((pa[0] + pa[1]) + (pa[2] + pa[3])) + ((pa[4] + pa[5]) + (pa[6] + pa[7])) +
                 (((pa[8] + pa[9]) + (pa[10] + pa[11])) + ((pa[12] + pa[13]) + (pa[14] + pa[15])));
      l_r += rs;

      // P^T -> B-fragments: straight in-order pairwise packs (sigma layout)
      union BP { u32 u[4]; bf16x8 v; } f0, f1;
      f0.u[0] = pkbf(pa[0], pa[1]);   f0.u[1] = pkbf(pa[2], pa[3]);
      f0.u[2] = pkbf(pa[4], pa[5]);   f0.u[3] = pkbf(pa[6], pa[7]);
      f1.u[0] = pkbf(pa[8], pa[9]);   f1.u[1] = pkbf(pa[10], pa[11]);
      f1.u[2] = pkbf(pa[12], pa[13]); f1.u[3] = pkbf(pa[14], pa[15]);

      // O^T += V^T * P^T
      __builtin_amdgcn_s_setprio(1);
#pragma unroll
      for (int dt = 0; dt < 2; ++dt) {
        const bf16* vrow = VtC + dt * 2048 + vbase;
        bf16x8 v0 = *(const bf16x8*)(vrow + (((p * 4 + hi) ^ vslotx) * 8));
        acc[dt] = mfma32(v0, f0.v, acc[dt]);
        bf16x8 v1 = *(const bf16x8*)(vrow + (((p * 4 + 2 + hi) ^ vslotx) * 8));
        acc[dt] = mfma32(v1, f1.v, acc[dt]);
      }
      __builtin_amdgcn_s_setprio(0);
    }
  }

  // ---- split-KV merge: waves (0,1) and (2,3) combine (m, l, acc) ----
  __syncthreads();   // everyone done with Ks/Vt; LDS reused
  float* fs = (float*)smem;          // 2 x 64 x 34 floats = 17.4 KB merge area
  if (wid & 1) {
    float* mb = fs + (wid >> 1) * 2176 + lane * 34;
#pragma unroll
    for (int dt = 0; dt < 2; ++dt)
#pragma unroll
      for (int r = 0; r < 16; ++r) mb[dt * 16 + r] = acc[dt][r];
    mb[32] = m_r;
    mb[33] = l_r;
  }
  __syncthreads();
  if (!(wid & 1)) {
    const float* mb = fs + (wid >> 1) * 2176 + lane * 34;
    float m1 = mb[32], l1 = mb[33];
    float ms = fmaxf(m_r, m1);
    float e0 = fexp2(m_r - ms), e1 = fexp2(m1 - ms);
    l_r = l_r * e0 + l1 * e1;
#pragma unroll
    for (int dt = 0; dt < 2; ++dt)
#pragma unroll
      for (int r = 0; r < 16; ++r)
        acc[dt][r] = acc[dt][r] * e0 + mb[dt * 16 + r] * e1;

    // O^T regs -> per-tile LDS transpose scratch (beyond the merge area)
    const float l_tot = l_r + __shfl_xor(l_r, 32, 64);
    const float inv = 1.0f / l_tot;
    bf16* scr = smem + 10240 + (wid >> 1) * 2176;   // byte 20480+, 4.25KB each
#pragma unroll
    for (int dt = 0; dt < 2; ++dt)
#pragma unroll
      for (int g2 = 0; g2 < 4; ++g2) {
        union { u16 hh[4]; unsigned long long q8; } pk4;
#pragma unroll
        for (int j = 0; j < 4; ++j) pk4.hh[j] = f2b(acc[dt][g2 * 4 + j] * inv);
        *(unsigned long long*)(scr + l31 * 68 + dt * 32 + g2 * 8 + 4 * hi) = pk4.q8;
      }
  }
  __syncthreads();   // scratch visible for cross-lane reads
  if (!(wid & 1)) {
    const bf16* scr = smem + 10240 + (wid >> 1) * 2176;
    const int qe = lane >> 1, he = lane & 1;
    u16* cp = (u16*)ctx + (long)(q0w + qe) * DMODEL + h * HD + he * 32;
#pragma unroll
    for (int j = 0; j < 4; ++j) {
      u16x8 v = *(const u16x8*)(scr + qe * 68 + he * 32 + j * 8);
      *(u16x8*)(cp + j * 8) = v;
    }
  }
}

extern "C" void kernel_launch(void* const* d_in, const int* in_sizes, int n_in,
                              void* d_out, int out_size, void* d_ws, size_t ws_size,
                              hipStream_t stream) {
  (void)in_sizes; (void)n_in; (void)out_size; (void)ws_size;
  const float* x  = (const float*)d_in[0];
  const float* Wq = (const float*)d_in[1];
  const float* Wk = (const float*)d_in[2];
  const float* Wv = (const float*)d_in[3];
  const float* Wo = (const float*)d_in[4];
  const float* bo = (const float*)d_in[5];
  float* out = (float*)d_out;

  char* ws = (char*)d_ws;
  bf16* xb  = (bf16*)(ws);                    //  8 MB: x bf16 [4096,1024]
  bf16* wqk = (bf16*)(ws + 8388608);          //  4 MB: Wq;Wk [2048,1024]
  bf16* wvb = (bf16*)(ws + 12582912);         //  2 MB: Wv [1024,1024]
  bf16* wob = (bf16*)(ws + 14680064);         //  2 MB: Wo [1024,1024]
  bf16* qkb = (bf16*)(ws + 16777216);         // 16 MB: QK [4096,2048]
  bf16* vtb = (bf16*)(ws + 33554432);         //  8 MB: V^T [1024,4096]
  bf16* ctxb = (bf16*)(ws + 41943040);        //  8 MB: ctx [4096,1024]
  float2* tab = (float2*)(ws + 50331648);     //  1 MB: RoPE trig table

  cvt5_kernel<<<dim3(8704), dim3(256), 0, stream>>>(x, Wq, Wk, Wv, Wo,
                                                    xb, wqk, wvb, wob, tab);
  gemm_qkv<<<dim3(768), dim3(256), 0, stream>>>(xb, wqk, wvb, qkb, vtb);
  rope_kernel<<<dim3(4096), dim3(256), 0, stream>>>(qkb, tab);
  attn_kernel<<<dim3(1024), dim3(256), 0, stream>>>(qkb, vtb, ctxb);
  gemm_bt<0><<<dim3(8, 32), dim3(256), 0, stream>>>(ctxb, wob, (void*)out, bo,
                                                    4096, 1024, 1024);
}